// Round 7
// baseline (506.034 us; speedup 1.0000x reference)
//
#include <hip/hip_runtime.h>

#define CELL 50.0f
#define N_TABLE 1024
#define NBUCK 256            // self-buckets
#define SELF 392             // atoms per self-bucket (const => cheap div); NBUCK*SELF=100352
#define PANEL 2048           // atoms per other-panel
#define NPAN 49              // ceil(100352/2048)
#define NBINS (NBUCK * NPAN) // 12544
#define NBLK 128             // hist/scatter blocks
#define THREADS 256
#define RED_THREADS 512
#define NREP 2               // acc replicas in reduce

typedef unsigned int uint;

__device__ __forceinline__ uint bucket_of(uint a) { return a / SELF; }

// ---------------- K0: pack q into float4 ----------------
__global__ __launch_bounds__(THREADS) void pack_q4_kernel(
    const float* __restrict__ q, float4* __restrict__ q4, int n_atoms)
{
    int i = blockIdx.x * THREADS + threadIdx.x;
    if (i < n_atoms)
        q4[i] = make_float4(q[3 * i], q[3 * i + 1], q[3 * i + 2], 0.0f);
}

// ---------------- K1: per-block 2D-bin histogram ----------------
// bin(self=i, other=j) = (i/SELF)*NPAN + (j>>11)
__global__ __launch_bounds__(THREADS) void hist_kernel(
    const int2* __restrict__ nbr, uint* __restrict__ partial, int n_pairs, int ppb)
{
    __shared__ uint h[NBINS];
    for (int k = threadIdx.x; k < NBINS; k += THREADS) h[k] = 0;
    __syncthreads();
    int start = blockIdx.x * ppb;                 // ppb even
    int end   = min(start + ppb, n_pairs & ~1);
    const int4* nbr4 = (const int4*)nbr;
    for (int p2 = (start >> 1) + threadIdx.x; p2 < (end >> 1); p2 += THREADS) {
        int4 v = nbr4[p2];
        uint i0 = (uint)v.x, j0 = (uint)v.y, i1 = (uint)v.z, j1 = (uint)v.w;
        atomicAdd(&h[bucket_of(i0) * NPAN + (j0 >> 11)], 1u);
        atomicAdd(&h[bucket_of(j0) * NPAN + (i0 >> 11)], 1u);
        atomicAdd(&h[bucket_of(i1) * NPAN + (j1 >> 11)], 1u);
        atomicAdd(&h[bucket_of(j1) * NPAN + (i1 >> 11)], 1u);
    }
    if (blockIdx.x == 0 && threadIdx.x == 0 && (n_pairs & 1)) {
        int2 ij = nbr[n_pairs - 1];
        uint i = (uint)ij.x, j = (uint)ij.y;
        atomicAdd(&h[bucket_of(i) * NPAN + (j >> 11)], 1u);
        atomicAdd(&h[bucket_of(j) * NPAN + (i >> 11)], 1u);
    }
    __syncthreads();
    // transposed layout: partial[blk*NBINS + bin] (coalesced store)
    for (int k = threadIdx.x; k < NBINS; k += THREADS)
        partial[blockIdx.x * NBINS + k] = h[k];
}

// ---------------- K2a: per-bin exclusive scan across the NBLK blocks ----------------
__global__ __launch_bounds__(NBLK) void scan_rows_kernel(
    uint* __restrict__ partial, uint* __restrict__ binTotal)
{
    __shared__ uint s[NBLK];
    int bin = blockIdx.x;
    uint v = partial[threadIdx.x * NBINS + bin];
    s[threadIdx.x] = v;
    __syncthreads();
    for (int off = 1; off < NBLK; off <<= 1) {
        uint t = (threadIdx.x >= (uint)off) ? s[threadIdx.x - off] : 0u;
        __syncthreads();
        s[threadIdx.x] += t;
        __syncthreads();
    }
    partial[threadIdx.x * NBINS + bin] = s[threadIdx.x] - v;   // exclusive within bin
    if (threadIdx.x == NBLK - 1) binTotal[bin] = s[NBLK - 1];
}

// ---------------- K2b: exclusive scan of bin totals (NBINS = 256*NPAN) ----------------
__global__ __launch_bounds__(256) void scan_totals_kernel(
    const uint* __restrict__ binTotal, uint* __restrict__ binBase)
{
    __shared__ uint s[256];
    int base = threadIdx.x * NPAN;
    uint sum = 0;
    for (int k = 0; k < NPAN; k++) sum += binTotal[base + k];
    s[threadIdx.x] = sum;
    __syncthreads();
    for (int off = 1; off < 256; off <<= 1) {
        uint t = (threadIdx.x >= (uint)off) ? s[threadIdx.x - off] : 0u;
        __syncthreads();
        s[threadIdx.x] += t;
        __syncthreads();
    }
    uint run = s[threadIdx.x] - sum;   // exclusive prefix of this thread's group
    for (int k = 0; k < NPAN; k++) { binBase[base + k] = run; run += binTotal[base + k]; }
    if (threadIdx.x == 255) binBase[NBINS] = run;
}

// ---------------- K3: scatter packed entries into (bucket,panel) bins ----------------
// entry = (other << 9) | (self % SELF)   [SELF=392 < 512, other < 131072]
__global__ __launch_bounds__(THREADS) void scatter_kernel(
    const int2* __restrict__ nbr, const uint* __restrict__ partial,
    const uint* __restrict__ binBase, uint* __restrict__ entries,
    int n_pairs, int ppb)
{
    __shared__ uint cur[NBINS];
    for (int k = threadIdx.x; k < NBINS; k += THREADS)
        cur[k] = binBase[k] + partial[blockIdx.x * NBINS + k];
    __syncthreads();
    int start = blockIdx.x * ppb;
    int end   = min(start + ppb, n_pairs & ~1);
    const int4* nbr4 = (const int4*)nbr;
    for (int p2 = (start >> 1) + threadIdx.x; p2 < (end >> 1); p2 += THREADS) {
        int4 v = nbr4[p2];
        uint i0 = (uint)v.x, j0 = (uint)v.y, i1 = (uint)v.z, j1 = (uint)v.w;
        uint p;
        p = atomicAdd(&cur[bucket_of(i0) * NPAN + (j0 >> 11)], 1u);
        entries[p] = (j0 << 9) | (i0 - bucket_of(i0) * SELF);
        p = atomicAdd(&cur[bucket_of(j0) * NPAN + (i0 >> 11)], 1u);
        entries[p] = (i0 << 9) | (j0 - bucket_of(j0) * SELF);
        p = atomicAdd(&cur[bucket_of(i1) * NPAN + (j1 >> 11)], 1u);
        entries[p] = (j1 << 9) | (i1 - bucket_of(i1) * SELF);
        p = atomicAdd(&cur[bucket_of(j1) * NPAN + (i1 >> 11)], 1u);
        entries[p] = (i1 << 9) | (j1 - bucket_of(j1) * SELF);
    }
    if (blockIdx.x == 0 && threadIdx.x == 0 && (n_pairs & 1)) {
        int2 ij = nbr[n_pairs - 1];
        uint i = (uint)ij.x, j = (uint)ij.y;
        uint p;
        p = atomicAdd(&cur[bucket_of(i) * NPAN + (j >> 11)], 1u);
        entries[p] = (j << 9) | (i - bucket_of(i) * SELF);
        p = atomicAdd(&cur[bucket_of(j) * NPAN + (i >> 11)], 1u);
        entries[p] = (i << 9) | (j - bucket_of(j) * SELF);
    }
}

// ---------------- K4: per-bucket reduce, panels staged in LDS (no random global gathers) ----------------
__global__ __launch_bounds__(RED_THREADS) void reduce_kernel(
    const float4* __restrict__ q4,
    const float* __restrict__ table_r, const float* __restrict__ table_f,
    const uint* __restrict__ binBase, const uint* __restrict__ entries,
    float* __restrict__ force, int n_atoms)
{
    __shared__ float2 tfp[N_TABLE];        // (f[i], f[i+1]-f[i])       8 KB
    __shared__ float4 qs[SELF];            // self-bucket positions     6.3 KB
    __shared__ float4 qp[PANEL];           // current other-panel       32 KB
    __shared__ float  acc[NREP * SELF * 3];//                           9.4 KB

    int b = blockIdx.x;
    int atomBase = b * SELF;
    if (atomBase >= n_atoms) return;
    int nA = min(SELF, n_atoms - atomBase);

    const float r0     = table_r[0];
    const float rend   = table_r[N_TABLE - 1];
    const float inv_dr = (float)(N_TABLE - 1) / (rend - r0);

    for (int k = threadIdx.x; k < N_TABLE - 1; k += RED_THREADS) {
        float a = table_f[k], c = table_f[k + 1];
        tfp[k] = make_float2(a, c - a);
    }
    for (int k = threadIdx.x; k < nA; k += RED_THREADS) qs[k] = q4[atomBase + k];
    for (int k = threadIdx.x; k < NREP * SELF * 3; k += RED_THREADS) acc[k] = 0.0f;
    __syncthreads();

    float* myacc = &acc[((threadIdx.x >> 6) & (NREP - 1)) * (SELF * 3)];

    for (int p = 0; p < NPAN; ++p) {
        int pbase = p << 11;
        int pA = min(PANEL, n_atoms - pbase);
        if (pA <= 0) break;
        // stage panel (coalesced)
        for (int k = threadIdx.x; k < pA; k += RED_THREADS) qp[k] = q4[pbase + k];
        __syncthreads();

        uint bin = (uint)b * NPAN + (uint)p;
        uint e0 = binBase[bin], e1 = binBase[bin + 1];
        for (uint e = e0 + threadIdx.x; e < e1; e += RED_THREADS) {
            uint ev = entries[e];
            int local = (int)(ev & 511u);
            int lidx  = (int)(ev >> 9) - pbase;
            float4 o = qp[lidx];
            float4 m = qs[local];
            float dx = m.x - o.x, dy = m.y - o.y, dz = m.z - o.z;
            dx -= CELL * rintf(dx / CELL);
            dy -= CELL * rintf(dy / CELL);
            dz -= CELL * rintf(dz / CELL);
            float r   = sqrtf(dx * dx + dy * dy + dz * dz);
            float inv = 1.0f / fmaxf(r, 1e-12f);
            float t   = (r - r0) * inv_dr;
            t = fminf(fmaxf(t, 0.0f), 1023.0f);
            int idx = min((int)t, N_TABLE - 2);
            float frac = t - (float)idx;
            float2 tp = tfp[idx];
            float s = (tp.x + frac * tp.y) * inv;
            atomicAdd(&myacc[local * 3 + 0], s * dx);
            atomicAdd(&myacc[local * 3 + 1], s * dy);
            atomicAdd(&myacc[local * 3 + 2], s * dz);
        }
        __syncthreads();   // protect qp before next stage
    }

    for (int k = threadIdx.x; k < nA * 3; k += RED_THREADS) {
        float s = 0.0f;
        #pragma unroll
        for (int rp = 0; rp < NREP; rp++) s += acc[rp * (SELF * 3) + k];
        force[atomBase * 3 + k] = s;
    }
}

// ---------------- fallback: proven global-atomic kernel ----------------
__global__ __launch_bounds__(THREADS) void pair_force_atomic_kernel(
    const float* __restrict__ q, const int2* __restrict__ nbr,
    const float* __restrict__ table_r, const float* __restrict__ table_f,
    float* __restrict__ force, int n_pairs)
{
    __shared__ float tr[N_TABLE];
    __shared__ float tf[N_TABLE];
    for (int k = threadIdx.x; k < N_TABLE; k += THREADS) { tr[k] = table_r[k]; tf[k] = table_f[k]; }
    __syncthreads();
    const float r0 = tr[0], rend = tr[N_TABLE - 1];
    const float inv_dr = (float)(N_TABLE - 1) / (rend - r0);
    int p = blockIdx.x * THREADS + threadIdx.x;
    if (p >= n_pairs) return;
    int2 ij = nbr[p];
    int i = ij.x, j = ij.y;
    float dx = q[3 * i] - q[3 * j], dy = q[3 * i + 1] - q[3 * j + 1], dz = q[3 * i + 2] - q[3 * j + 2];
    dx -= CELL * rintf(dx / CELL); dy -= CELL * rintf(dy / CELL); dz -= CELL * rintf(dz / CELL);
    float r = sqrtf(dx * dx + dy * dy + dz * dz);
    float inv = 1.0f / fmaxf(r, 1e-12f);
    float fm;
    if (r <= r0) fm = tf[0];
    else if (r >= rend) fm = tf[N_TABLE - 1];
    else {
        float t = (r - r0) * inv_dr;
        int idx = min(max((int)t, 0), N_TABLE - 2);
        if (r < tr[idx]) idx = max(idx - 1, 0);
        else if (r >= tr[idx + 1]) idx = min(idx + 1, N_TABLE - 2);
        float rl = tr[idx], rh = tr[idx + 1];
        fm = tf[idx] + (r - rl) * (tf[idx + 1] - tf[idx]) / (rh - rl);
    }
    float s = fm * inv;
    float fx = s * dx, fy = s * dy, fz = s * dz;
    atomicAdd(&force[3 * i + 0], fx); atomicAdd(&force[3 * i + 1], fy); atomicAdd(&force[3 * i + 2], fz);
    atomicAdd(&force[3 * j + 0], -fx); atomicAdd(&force[3 * j + 1], -fy); atomicAdd(&force[3 * j + 2], -fz);
}

extern "C" void kernel_launch(void* const* d_in, const int* in_sizes, int n_in,
                              void* d_out, int out_size, void* d_ws, size_t ws_size,
                              hipStream_t stream) {
    const float* q       = (const float*)d_in[0];
    const int2*  nbr     = (const int2*)d_in[1];
    const float* table_r = (const float*)d_in[2];
    const float* table_f = (const float*)d_in[3];
    float*       force   = (float*)d_out;

    const int n_pairs = in_sizes[1] / 2;
    const int n_atoms = in_sizes[0] / 3;

    // workspace layout (256B-aligned)
    size_t off_partial  = 0;
    size_t off_binTotal = (off_partial + (size_t)NBLK * NBINS * 4 + 255) & ~255ull;   // 6.4 MB
    size_t off_binBase  = (off_binTotal + (size_t)NBINS * 4 + 255) & ~255ull;
    size_t off_entries  = (off_binBase + (size_t)(NBINS + 1) * 4 + 255) & ~255ull;
    size_t off_q4       = (off_entries + (size_t)2 * n_pairs * 4 + 255) & ~255ull;
    size_t need         = off_q4 + (size_t)n_atoms * 16;

    if (ws_size < need || n_atoms > NBUCK * SELF) {
        hipMemsetAsync(d_out, 0, (size_t)out_size * sizeof(float), stream);
        int blocks = (n_pairs + THREADS - 1) / THREADS;
        pair_force_atomic_kernel<<<blocks, THREADS, 0, stream>>>(q, nbr, table_r, table_f, force, n_pairs);
        return;
    }

    char* ws = (char*)d_ws;
    uint*   partial  = (uint*)(ws + off_partial);
    uint*   binTotal = (uint*)(ws + off_binTotal);
    uint*   binBase  = (uint*)(ws + off_binBase);
    uint*   entries  = (uint*)(ws + off_entries);
    float4* q4       = (float4*)(ws + off_q4);

    int ppb = (((n_pairs + NBLK - 1) / NBLK) + 1) & ~1;   // even pairs per block

    int pb = (n_atoms + THREADS - 1) / THREADS;
    pack_q4_kernel<<<pb, THREADS, 0, stream>>>(q, q4, n_atoms);
    hist_kernel<<<NBLK, THREADS, 0, stream>>>(nbr, partial, n_pairs, ppb);
    scan_rows_kernel<<<NBINS, NBLK, 0, stream>>>(partial, binTotal);
    scan_totals_kernel<<<1, 256, 0, stream>>>(binTotal, binBase);
    scatter_kernel<<<NBLK, THREADS, 0, stream>>>(nbr, partial, binBase, entries, n_pairs, ppb);
    reduce_kernel<<<NBUCK, RED_THREADS, 0, stream>>>(q4, table_r, table_f, binBase, entries, force, n_atoms);
}

// Round 8
// 287.778 us; speedup vs baseline: 1.7584x; 1.7584x over previous
//
#include <hip/hip_runtime.h>

#define CELL 50.0f
#define N_TABLE 1024
#define NB 1024            // buckets of 128 atoms each (max 131072 atoms)
#define NBLK 1024          // histogram/scatter blocks
#define THREADS 256
#define RED_THREADS 512
#define NREP 8             // one acc replica per wave in reduce (REQUIRED: wave-private)
#define BATCH 6            // entries per thread per chunk in reduce

typedef unsigned int uint;

// ---------------- K0: pack q into float4 ----------------
__global__ __launch_bounds__(THREADS) void pack_q4_kernel(
    const float* __restrict__ q, float4* __restrict__ q4, int n_atoms)
{
    int i = blockIdx.x * THREADS + threadIdx.x;
    if (i < n_atoms)
        q4[i] = make_float4(q[3 * i], q[3 * i + 1], q[3 * i + 2], 0.0f);
}

// ---------------- K1: per-block bucket histogram (int4 loads) ----------------
__global__ __launch_bounds__(THREADS) void hist_kernel(
    const int2* __restrict__ nbr, uint* __restrict__ partial, int n_pairs, int ppb)
{
    __shared__ uint h[NB];
    for (int k = threadIdx.x; k < NB; k += THREADS) h[k] = 0;
    __syncthreads();
    int start = blockIdx.x * ppb;                 // ppb even -> start even
    int end   = min(start + ppb, n_pairs & ~1);
    const int4* nbr4 = (const int4*)nbr;
    for (int p2 = (start >> 1) + threadIdx.x; p2 < (end >> 1); p2 += THREADS) {
        int4 v = nbr4[p2];
        atomicAdd(&h[((uint)v.x) >> 7], 1u);
        atomicAdd(&h[((uint)v.y) >> 7], 1u);
        atomicAdd(&h[((uint)v.z) >> 7], 1u);
        atomicAdd(&h[((uint)v.w) >> 7], 1u);
    }
    if (blockIdx.x == 0 && threadIdx.x == 0 && (n_pairs & 1)) {
        int2 ij = nbr[n_pairs - 1];
        atomicAdd(&h[((uint)ij.x) >> 7], 1u);
        atomicAdd(&h[((uint)ij.y) >> 7], 1u);
    }
    __syncthreads();
    for (int k = threadIdx.x; k < NB; k += THREADS)
        partial[k * NBLK + blockIdx.x] = h[k];
}

// ---------------- K2a: per-bucket exclusive scan over block partials ----------------
__global__ __launch_bounds__(THREADS) void scan_rows_kernel(
    uint* __restrict__ partial, uint* __restrict__ binTotal)
{
    __shared__ uint s[THREADS];
    int bin = blockIdx.x;
    uint running = 0;
    for (int c = 0; c < NBLK / THREADS; c++) {
        int idx = bin * NBLK + c * THREADS + threadIdx.x;
        uint v = partial[idx];
        s[threadIdx.x] = v;
        __syncthreads();
        for (int off = 1; off < THREADS; off <<= 1) {
            uint t = (threadIdx.x >= (uint)off) ? s[threadIdx.x - off] : 0u;
            __syncthreads();
            s[threadIdx.x] += t;
            __syncthreads();
        }
        partial[idx] = running + s[threadIdx.x] - v;   // exclusive within bin
        uint csum = s[THREADS - 1];
        __syncthreads();
        running += csum;
    }
    if (threadIdx.x == 0) binTotal[bin] = running;
}

// ---------------- K2b: exclusive scan of bucket totals ----------------
__global__ __launch_bounds__(THREADS) void scan_totals_kernel(
    const uint* __restrict__ binTotal, uint* __restrict__ binBase)
{
    __shared__ uint s[THREADS];
    uint v[4];
    uint sum = 0;
    int base = threadIdx.x * 4;
    for (int k = 0; k < 4; k++) { v[k] = binTotal[base + k]; sum += v[k]; }
    s[threadIdx.x] = sum;
    __syncthreads();
    for (int off = 1; off < THREADS; off <<= 1) {
        uint t = (threadIdx.x >= (uint)off) ? s[threadIdx.x - off] : 0u;
        __syncthreads();
        s[threadIdx.x] += t;
        __syncthreads();
    }
    uint run = s[threadIdx.x] - sum;
    for (int k = 0; k < 4; k++) { binBase[base + k] = run; run += v[k]; }
    if (threadIdx.x == THREADS - 1) binBase[NB] = run;
}

// ---------------- K3: scatter packed entries (int4 loads) ----------------
// entry = (other_atom << 7) | (self_atom & 127); self's bucket = self >> 7.
__global__ __launch_bounds__(THREADS) void scatter_kernel(
    const int2* __restrict__ nbr, const uint* __restrict__ partial,
    const uint* __restrict__ binBase, uint* __restrict__ entries,
    int n_pairs, int ppb)
{
    __shared__ uint cur[NB];
    for (int k = threadIdx.x; k < NB; k += THREADS)
        cur[k] = binBase[k] + partial[k * NBLK + blockIdx.x];
    __syncthreads();
    int start = blockIdx.x * ppb;
    int end   = min(start + ppb, n_pairs & ~1);
    const int4* nbr4 = (const int4*)nbr;
    for (int p2 = (start >> 1) + threadIdx.x; p2 < (end >> 1); p2 += THREADS) {
        int4 v = nbr4[p2];
        uint i0 = (uint)v.x, j0 = (uint)v.y, i1 = (uint)v.z, j1 = (uint)v.w;
        uint p;
        p = atomicAdd(&cur[i0 >> 7], 1u); entries[p] = (j0 << 7) | (i0 & 127u);
        p = atomicAdd(&cur[j0 >> 7], 1u); entries[p] = (i0 << 7) | (j0 & 127u);
        p = atomicAdd(&cur[i1 >> 7], 1u); entries[p] = (j1 << 7) | (i1 & 127u);
        p = atomicAdd(&cur[j1 >> 7], 1u); entries[p] = (i1 << 7) | (j1 & 127u);
    }
    if (blockIdx.x == 0 && threadIdx.x == 0 && (n_pairs & 1)) {
        int2 ij = nbr[n_pairs - 1];
        uint i = (uint)ij.x, j = (uint)ij.y;
        uint p;
        p = atomicAdd(&cur[i >> 7], 1u); entries[p] = (j << 7) | (i & 127u);
        p = atomicAdd(&cur[j >> 7], 1u); entries[p] = (i << 7) | (j & 127u);
    }
}

// ---------------- K4: per-bucket reduce (ballot-dedup, atomic-free fast path) ----------------
// accw: THIS wave's private float4 replica (accv + waveid*128).
// Collision rule: if `local` is unique within the wave -> plain LDS RMW (banked,
// parallel). Else ALL holders take atomicAdd -> no mixed-path race on an address.
__device__ __forceinline__ void proc_entry(
    uint ev, float ox, float oy, float oz,
    const float4* __restrict__ qs, const float2* __restrict__ tfp,
    float4* __restrict__ accw, float r0, float inv_dr, int lane)
{
    int local = (int)(ev & 127u);
    float4 m = qs[local];
    float dx = m.x - ox, dy = m.y - oy, dz = m.z - oz;
    // exact minimum image for d in (-50,50): round-half-even boundary at +/-25.0
    dx -= (dx > 25.0f) ? 50.0f : ((dx < -25.0f) ? -50.0f : 0.0f);
    dy -= (dy > 25.0f) ? 50.0f : ((dy < -25.0f) ? -50.0f : 0.0f);
    dz -= (dz > 25.0f) ? 50.0f : ((dz < -25.0f) ? -50.0f : 0.0f);
    float r2 = dx * dx + dy * dy + dz * dz;
    float rs = __builtin_amdgcn_rsqf(fmaxf(r2, 1e-24f));   // ~1ulp v_rsq_f32
    float r  = r2 * rs;                                    // r = sqrt(r2)
    float t  = (r - r0) * inv_dr;
    t = fminf(fmaxf(t, 0.0f), 1023.0f);
    int idx = min((int)t, N_TABLE - 2);
    float frac = t - (float)idx;
    float2 tp = tfp[idx];
    float s = (tp.x + frac * tp.y) * rs;                   // fm / r
    float fx = s * dx, fy = s * dy, fz = s * dz;

    // 7-bit ballot grouping of `local` within the wave
    unsigned long long m64 = __ballot(1);                  // active mask
    #pragma unroll
    for (int b = 0; b < 7; b++) {
        unsigned long long bb = __ballot((local >> b) & 1);
        m64 &= ((local >> b) & 1) ? bb : ~bb;
    }
    if (m64 == (1ull << lane)) {
        float4 a = accw[local];
        a.x += fx; a.y += fy; a.z += fz;
        accw[local] = a;
    } else {
        atomicAdd(&accw[local].x, fx);
        atomicAdd(&accw[local].y, fy);
        atomicAdd(&accw[local].z, fz);
    }
}

template<int USE_Q4>
__global__ __launch_bounds__(RED_THREADS, 8) void reduce_kernel(
    const float* __restrict__ q, const float4* __restrict__ q4,
    const float* __restrict__ table_r, const float* __restrict__ table_f,
    const uint* __restrict__ binBase, const uint* __restrict__ entries,
    float* __restrict__ force, int n_atoms)
{
    __shared__ float2 tfp[N_TABLE];        // (f[i], f[i+1]-f[i])   8 KB
    __shared__ float4 qs[128];             //                       2 KB
    __shared__ float4 accv[NREP * 128];    // wave-private replicas 16 KB

    int b = blockIdx.x;
    int atomBase = b << 7;
    if (atomBase >= n_atoms) return;
    int nA = min(128, n_atoms - atomBase);
    int lane = threadIdx.x & 63;

    const float r0     = table_r[0];
    const float rend   = table_r[N_TABLE - 1];
    const float inv_dr = (float)(N_TABLE - 1) / (rend - r0);

    for (int k = threadIdx.x; k < N_TABLE - 1; k += RED_THREADS) {
        float a = table_f[k], c = table_f[k + 1];
        tfp[k] = make_float2(a, c - a);
    }
    for (int k = threadIdx.x; k < nA; k += RED_THREADS) {
        if (USE_Q4) qs[k] = q4[atomBase + k];
        else qs[k] = make_float4(q[(atomBase + k) * 3], q[(atomBase + k) * 3 + 1],
                                 q[(atomBase + k) * 3 + 2], 0.0f);
    }
    for (int k = threadIdx.x; k < NREP * 128; k += RED_THREADS)
        accv[k] = make_float4(0.0f, 0.0f, 0.0f, 0.0f);
    __syncthreads();

    float4* accw = &accv[(threadIdx.x >> 6) * 128];

    uint e0 = binBase[b], e1 = binBase[b + 1];
    uint count = e1 - e0;
    const uint CHUNK = BATCH * RED_THREADS;
    uint nmain = (count / CHUNK) * CHUNK;

    if (nmain) {
        uint v[BATCH];
        #pragma unroll
        for (int k = 0; k < BATCH; k++)
            v[k] = entries[e0 + threadIdx.x + k * RED_THREADS];

        for (uint base = 0; base < nmain; ) {
            float ox[BATCH], oy[BATCH], oz[BATCH];
            #pragma unroll
            for (int k = 0; k < BATCH; k++) {
                uint other = v[k] >> 7;
                if (USE_Q4) {
                    const float* p = (const float*)&q4[other];
                    ox[k] = p[0]; oy[k] = p[1]; oz[k] = p[2];
                } else {
                    ox[k] = q[3 * other]; oy[k] = q[3 * other + 1]; oz[k] = q[3 * other + 2];
                }
            }
            uint base_n = base + CHUNK;
            uint vn[BATCH];
            if (base_n < nmain) {
                #pragma unroll
                for (int k = 0; k < BATCH; k++)
                    vn[k] = entries[e0 + base_n + threadIdx.x + k * RED_THREADS];
            } else {
                #pragma unroll
                for (int k = 0; k < BATCH; k++) vn[k] = 0u;
            }
            #pragma unroll
            for (int k = 0; k < BATCH; k++)
                proc_entry(v[k], ox[k], oy[k], oz[k], qs, tfp, accw, r0, inv_dr, lane);
            #pragma unroll
            for (int k = 0; k < BATCH; k++) v[k] = vn[k];
            base = base_n;
        }
    }
    // tail (partially active waves OK: ballot uses live active mask)
    for (uint e = e0 + nmain + threadIdx.x; e < e1; e += RED_THREADS) {
        uint ev = entries[e];
        uint other = ev >> 7;
        float ox, oy, oz;
        if (USE_Q4) {
            const float* p = (const float*)&q4[other];
            ox = p[0]; oy = p[1]; oz = p[2];
        } else {
            ox = q[3 * other]; oy = q[3 * other + 1]; oz = q[3 * other + 2];
        }
        proc_entry(ev, ox, oy, oz, qs, tfp, accw, r0, inv_dr, lane);
    }

    __syncthreads();
    for (int k = threadIdx.x; k < nA; k += RED_THREADS) {
        float sx = 0.0f, sy = 0.0f, sz = 0.0f;
        #pragma unroll
        for (int rp = 0; rp < NREP; rp++) {
            float4 a = accv[rp * 128 + k];
            sx += a.x; sy += a.y; sz += a.z;
        }
        force[(atomBase + k) * 3 + 0] = sx;
        force[(atomBase + k) * 3 + 1] = sy;
        force[(atomBase + k) * 3 + 2] = sz;
    }
}

// ---------------- fallback: proven global-atomic kernel ----------------
__global__ __launch_bounds__(THREADS) void pair_force_atomic_kernel(
    const float* __restrict__ q, const int2* __restrict__ nbr,
    const float* __restrict__ table_r, const float* __restrict__ table_f,
    float* __restrict__ force, int n_pairs)
{
    __shared__ float tr[N_TABLE];
    __shared__ float tf[N_TABLE];
    for (int k = threadIdx.x; k < N_TABLE; k += THREADS) { tr[k] = table_r[k]; tf[k] = table_f[k]; }
    __syncthreads();
    const float r0 = tr[0], rend = tr[N_TABLE - 1];
    const float inv_dr = (float)(N_TABLE - 1) / (rend - r0);
    int p = blockIdx.x * THREADS + threadIdx.x;
    if (p >= n_pairs) return;
    int2 ij = nbr[p];
    int i = ij.x, j = ij.y;
    float dx = q[3 * i] - q[3 * j], dy = q[3 * i + 1] - q[3 * j + 1], dz = q[3 * i + 2] - q[3 * j + 2];
    dx -= CELL * rintf(dx / CELL); dy -= CELL * rintf(dy / CELL); dz -= CELL * rintf(dz / CELL);
    float r = sqrtf(dx * dx + dy * dy + dz * dz);
    float inv = 1.0f / fmaxf(r, 1e-12f);
    float fm;
    if (r <= r0) fm = tf[0];
    else if (r >= rend) fm = tf[N_TABLE - 1];
    else {
        float t = (r - r0) * inv_dr;
        int idx = min(max((int)t, 0), N_TABLE - 2);
        if (r < tr[idx]) idx = max(idx - 1, 0);
        else if (r >= tr[idx + 1]) idx = min(idx + 1, N_TABLE - 2);
        float rl = tr[idx], rh = tr[idx + 1];
        fm = tf[idx] + (r - rl) * (tf[idx + 1] - tf[idx]) / (rh - rl);
    }
    float s = fm * inv;
    float fx = s * dx, fy = s * dy, fz = s * dz;
    atomicAdd(&force[3 * i + 0], fx); atomicAdd(&force[3 * i + 1], fy); atomicAdd(&force[3 * i + 2], fz);
    atomicAdd(&force[3 * j + 0], -fx); atomicAdd(&force[3 * j + 1], -fy); atomicAdd(&force[3 * j + 2], -fz);
}

extern "C" void kernel_launch(void* const* d_in, const int* in_sizes, int n_in,
                              void* d_out, int out_size, void* d_ws, size_t ws_size,
                              hipStream_t stream) {
    const float* q       = (const float*)d_in[0];
    const int2*  nbr     = (const int2*)d_in[1];
    const float* table_r = (const float*)d_in[2];
    const float* table_f = (const float*)d_in[3];
    float*       force   = (float*)d_out;

    const int n_pairs = in_sizes[1] / 2;
    const int n_atoms = in_sizes[0] / 3;

    // workspace layout (256B-aligned)
    size_t off_partial  = 0;
    size_t off_binTotal = off_partial + (size_t)NB * NBLK * 4;           // 4 MB
    size_t off_binBase  = (off_binTotal + (size_t)NB * 4 + 255) & ~255ull;
    size_t off_entries  = (off_binBase + (size_t)(NB + 1) * 4 + 255) & ~255ull;
    size_t off_q4       = (off_entries + (size_t)2 * n_pairs * 4 + 255) & ~255ull;
    size_t need_base    = off_q4;                       // without q4
    size_t need_q4      = off_q4 + (size_t)n_atoms * 16;

    if (ws_size < need_base || n_atoms > NB * 128) {
        hipMemsetAsync(d_out, 0, (size_t)out_size * sizeof(float), stream);
        int blocks = (n_pairs + THREADS - 1) / THREADS;
        pair_force_atomic_kernel<<<blocks, THREADS, 0, stream>>>(q, nbr, table_r, table_f, force, n_pairs);
        return;
    }

    char* ws = (char*)d_ws;
    uint*   partial  = (uint*)(ws + off_partial);
    uint*   binTotal = (uint*)(ws + off_binTotal);
    uint*   binBase  = (uint*)(ws + off_binBase);
    uint*   entries  = (uint*)(ws + off_entries);
    float4* q4       = (float4*)(ws + off_q4);
    int use_q4 = (ws_size >= need_q4) ? 1 : 0;

    int ppb = (((n_pairs + NBLK - 1) / NBLK) + 1) & ~1;   // even pairs per block

    if (use_q4) {
        int pb = (n_atoms + THREADS - 1) / THREADS;
        pack_q4_kernel<<<pb, THREADS, 0, stream>>>(q, q4, n_atoms);
    }
    hist_kernel<<<NBLK, THREADS, 0, stream>>>(nbr, partial, n_pairs, ppb);
    scan_rows_kernel<<<NB, THREADS, 0, stream>>>(partial, binTotal);
    scan_totals_kernel<<<1, THREADS, 0, stream>>>(binTotal, binBase);
    scatter_kernel<<<NBLK, THREADS, 0, stream>>>(nbr, partial, binBase, entries, n_pairs, ppb);
    if (use_q4)
        reduce_kernel<1><<<NB, RED_THREADS, 0, stream>>>(q, q4, table_r, table_f, binBase, entries, force, n_atoms);
    else
        reduce_kernel<0><<<NB, RED_THREADS, 0, stream>>>(q, q4, table_r, table_f, binBase, entries, force, n_atoms);
}

// Round 9
// 234.493 us; speedup vs baseline: 2.1580x; 1.2272x over previous
//
#include <hip/hip_runtime.h>

#define CELL 50.0f
#define N_TABLE 1024
#define NB 1024            // buckets of 128 atoms each (max 131072 atoms)
#define NBLK 1024          // histogram/scatter blocks
#define THREADS 256
#define RED_THREADS 512
#define NREP 8             // one acc replica per wave in reduce (REQUIRED: wave-private)
#define BATCH 6            // entries per thread per chunk in reduce

typedef unsigned int uint;

// ---------------- K0: pack q into float4 ----------------
__global__ __launch_bounds__(THREADS) void pack_q4_kernel(
    const float* __restrict__ q, float4* __restrict__ q4, int n_atoms)
{
    int i = blockIdx.x * THREADS + threadIdx.x;
    if (i < n_atoms)
        q4[i] = make_float4(q[3 * i], q[3 * i + 1], q[3 * i + 2], 0.0f);
}

// ---------------- K1: per-block bucket histogram (int4 loads) ----------------
__global__ __launch_bounds__(THREADS) void hist_kernel(
    const int2* __restrict__ nbr, uint* __restrict__ partial, int n_pairs, int ppb)
{
    __shared__ uint h[NB];
    for (int k = threadIdx.x; k < NB; k += THREADS) h[k] = 0;
    __syncthreads();
    int start = blockIdx.x * ppb;                 // ppb even -> start even
    int end   = min(start + ppb, n_pairs & ~1);
    const int4* nbr4 = (const int4*)nbr;
    for (int p2 = (start >> 1) + threadIdx.x; p2 < (end >> 1); p2 += THREADS) {
        int4 v = nbr4[p2];
        atomicAdd(&h[((uint)v.x) >> 7], 1u);
        atomicAdd(&h[((uint)v.y) >> 7], 1u);
        atomicAdd(&h[((uint)v.z) >> 7], 1u);
        atomicAdd(&h[((uint)v.w) >> 7], 1u);
    }
    if (blockIdx.x == 0 && threadIdx.x == 0 && (n_pairs & 1)) {
        int2 ij = nbr[n_pairs - 1];
        atomicAdd(&h[((uint)ij.x) >> 7], 1u);
        atomicAdd(&h[((uint)ij.y) >> 7], 1u);
    }
    __syncthreads();
    for (int k = threadIdx.x; k < NB; k += THREADS)
        partial[k * NBLK + blockIdx.x] = h[k];
}

// ---------------- K2a: per-bucket exclusive scan over block partials ----------------
__global__ __launch_bounds__(THREADS) void scan_rows_kernel(
    uint* __restrict__ partial, uint* __restrict__ binTotal)
{
    __shared__ uint s[THREADS];
    int bin = blockIdx.x;
    uint running = 0;
    for (int c = 0; c < NBLK / THREADS; c++) {
        int idx = bin * NBLK + c * THREADS + threadIdx.x;
        uint v = partial[idx];
        s[threadIdx.x] = v;
        __syncthreads();
        for (int off = 1; off < THREADS; off <<= 1) {
            uint t = (threadIdx.x >= (uint)off) ? s[threadIdx.x - off] : 0u;
            __syncthreads();
            s[threadIdx.x] += t;
            __syncthreads();
        }
        partial[idx] = running + s[threadIdx.x] - v;   // exclusive within bin
        uint csum = s[THREADS - 1];
        __syncthreads();
        running += csum;
    }
    if (threadIdx.x == 0) binTotal[bin] = running;
}

// ---------------- K2b: exclusive scan of bucket totals ----------------
__global__ __launch_bounds__(THREADS) void scan_totals_kernel(
    const uint* __restrict__ binTotal, uint* __restrict__ binBase)
{
    __shared__ uint s[THREADS];
    uint v[4];
    uint sum = 0;
    int base = threadIdx.x * 4;
    for (int k = 0; k < 4; k++) { v[k] = binTotal[base + k]; sum += v[k]; }
    s[threadIdx.x] = sum;
    __syncthreads();
    for (int off = 1; off < THREADS; off <<= 1) {
        uint t = (threadIdx.x >= (uint)off) ? s[threadIdx.x - off] : 0u;
        __syncthreads();
        s[threadIdx.x] += t;
        __syncthreads();
    }
    uint run = s[threadIdx.x] - sum;
    for (int k = 0; k < 4; k++) { binBase[base + k] = run; run += v[k]; }
    if (threadIdx.x == THREADS - 1) binBase[NB] = run;
}

// ---------------- K3: scatter packed entries (int4 loads) ----------------
// entry = (other_atom << 7) | (self_atom & 127); self's bucket = self >> 7.
__global__ __launch_bounds__(THREADS) void scatter_kernel(
    const int2* __restrict__ nbr, const uint* __restrict__ partial,
    const uint* __restrict__ binBase, uint* __restrict__ entries,
    int n_pairs, int ppb)
{
    __shared__ uint cur[NB];
    for (int k = threadIdx.x; k < NB; k += THREADS)
        cur[k] = binBase[k] + partial[k * NBLK + blockIdx.x];
    __syncthreads();
    int start = blockIdx.x * ppb;
    int end   = min(start + ppb, n_pairs & ~1);
    const int4* nbr4 = (const int4*)nbr;
    for (int p2 = (start >> 1) + threadIdx.x; p2 < (end >> 1); p2 += THREADS) {
        int4 v = nbr4[p2];
        uint i0 = (uint)v.x, j0 = (uint)v.y, i1 = (uint)v.z, j1 = (uint)v.w;
        uint p;
        p = atomicAdd(&cur[i0 >> 7], 1u); entries[p] = (j0 << 7) | (i0 & 127u);
        p = atomicAdd(&cur[j0 >> 7], 1u); entries[p] = (i0 << 7) | (j0 & 127u);
        p = atomicAdd(&cur[i1 >> 7], 1u); entries[p] = (j1 << 7) | (i1 & 127u);
        p = atomicAdd(&cur[j1 >> 7], 1u); entries[p] = (i1 << 7) | (j1 & 127u);
    }
    if (blockIdx.x == 0 && threadIdx.x == 0 && (n_pairs & 1)) {
        int2 ij = nbr[n_pairs - 1];
        uint i = (uint)ij.x, j = (uint)ij.y;
        uint p;
        p = atomicAdd(&cur[i >> 7], 1u); entries[p] = (j << 7) | (i & 127u);
        p = atomicAdd(&cur[j >> 7], 1u); entries[p] = (i << 7) | (j & 127u);
    }
}

// ---------------- K4: per-bucket reduce (ballot-group + leader-shfl, ZERO atomics) ----------------
// Group lanes by `local` (7-bit ballot). Leader (lowest lane of group) pulls each
// member's force via __shfl (uniform loop; all shfl sources are active by
// construction since m64 is a subset of ballot(1)), then does ONE plain banked
// LDS RMW into this wave's private replica. Leaders in a wave have distinct
// locals -> race-free. No atomics anywhere.
__device__ __forceinline__ void proc_entry(
    uint ev, float ox, float oy, float oz,
    const float4* __restrict__ qs, const float2* __restrict__ tfp,
    float4* __restrict__ accw, float r0, float inv_dr, int lane)
{
    int local = (int)(ev & 127u);
    float4 m = qs[local];
    float dx = m.x - ox, dy = m.y - oy, dz = m.z - oz;
    // exact minimum image for d in (-50,50): round-half-even boundary at +/-25.0
    dx -= (dx > 25.0f) ? 50.0f : ((dx < -25.0f) ? -50.0f : 0.0f);
    dy -= (dy > 25.0f) ? 50.0f : ((dy < -25.0f) ? -50.0f : 0.0f);
    dz -= (dz > 25.0f) ? 50.0f : ((dz < -25.0f) ? -50.0f : 0.0f);
    float r2 = dx * dx + dy * dy + dz * dz;
    float rs = __builtin_amdgcn_rsqf(fmaxf(r2, 1e-24f));   // ~1ulp v_rsq_f32
    float r  = r2 * rs;                                    // r = sqrt(r2)
    float t  = (r - r0) * inv_dr;
    t = fminf(fmaxf(t, 0.0f), 1023.0f);
    int idx = min((int)t, N_TABLE - 2);
    float frac = t - (float)idx;
    float2 tp = tfp[idx];
    float s = (tp.x + frac * tp.y) * rs;                   // fm / r
    float fx = s * dx, fy = s * dy, fz = s * dz;

    // 7-bit ballot grouping of `local` within the wave (m64 subset of active mask)
    unsigned long long m64 = __ballot(1);
    #pragma unroll
    for (int b = 0; b < 7; b++) {
        unsigned long long bb = __ballot((local >> b) & 1);
        m64 &= ((local >> b) & 1) ? bb : ~bb;
    }
    unsigned long long self = 1ull << lane;
    bool leader = ((m64 & (self - 1ull)) == 0ull);
    unsigned long long rem = leader ? (m64 & ~self) : 0ull;

    while (__any(rem != 0ull)) {
        int src = rem ? (int)__builtin_ctzll(rem) : lane;
        float px = __shfl(fx, src);
        float py = __shfl(fy, src);
        float pz = __shfl(fz, src);
        if (rem) {
            fx += px; fy += py; fz += pz;
            rem &= rem - 1ull;
        }
    }
    if (leader) {
        float4 a = accw[local];
        a.x += fx; a.y += fy; a.z += fz;
        accw[local] = a;
    }
}

template<int USE_Q4>
__global__ __launch_bounds__(RED_THREADS, 8) void reduce_kernel(
    const float* __restrict__ q, const float4* __restrict__ q4,
    const float* __restrict__ table_r, const float* __restrict__ table_f,
    const uint* __restrict__ binBase, const uint* __restrict__ entries,
    float* __restrict__ force, int n_atoms)
{
    __shared__ float2 tfp[N_TABLE];        // (f[i], f[i+1]-f[i])   8 KB
    __shared__ float4 qs[128];             //                       2 KB
    __shared__ float4 accv[NREP * 128];    // wave-private replicas 16 KB

    int b = blockIdx.x;
    int atomBase = b << 7;
    if (atomBase >= n_atoms) return;
    int nA = min(128, n_atoms - atomBase);
    int lane = threadIdx.x & 63;

    const float r0     = table_r[0];
    const float rend   = table_r[N_TABLE - 1];
    const float inv_dr = (float)(N_TABLE - 1) / (rend - r0);

    for (int k = threadIdx.x; k < N_TABLE - 1; k += RED_THREADS) {
        float a = table_f[k], c = table_f[k + 1];
        tfp[k] = make_float2(a, c - a);
    }
    for (int k = threadIdx.x; k < nA; k += RED_THREADS) {
        if (USE_Q4) qs[k] = q4[atomBase + k];
        else qs[k] = make_float4(q[(atomBase + k) * 3], q[(atomBase + k) * 3 + 1],
                                 q[(atomBase + k) * 3 + 2], 0.0f);
    }
    for (int k = threadIdx.x; k < NREP * 128; k += RED_THREADS)
        accv[k] = make_float4(0.0f, 0.0f, 0.0f, 0.0f);
    __syncthreads();

    float4* accw = &accv[(threadIdx.x >> 6) * 128];

    uint e0 = binBase[b], e1 = binBase[b + 1];
    uint count = e1 - e0;
    const uint CHUNK = BATCH * RED_THREADS;
    uint nmain = (count / CHUNK) * CHUNK;

    if (nmain) {
        uint v[BATCH];
        #pragma unroll
        for (int k = 0; k < BATCH; k++)
            v[k] = entries[e0 + threadIdx.x + k * RED_THREADS];

        for (uint base = 0; base < nmain; ) {
            float ox[BATCH], oy[BATCH], oz[BATCH];
            #pragma unroll
            for (int k = 0; k < BATCH; k++) {
                uint other = v[k] >> 7;
                if (USE_Q4) {
                    const float* p = (const float*)&q4[other];
                    ox[k] = p[0]; oy[k] = p[1]; oz[k] = p[2];
                } else {
                    ox[k] = q[3 * other]; oy[k] = q[3 * other + 1]; oz[k] = q[3 * other + 2];
                }
            }
            uint base_n = base + CHUNK;
            uint vn[BATCH];
            if (base_n < nmain) {
                #pragma unroll
                for (int k = 0; k < BATCH; k++)
                    vn[k] = entries[e0 + base_n + threadIdx.x + k * RED_THREADS];
            } else {
                #pragma unroll
                for (int k = 0; k < BATCH; k++) vn[k] = 0u;
            }
            #pragma unroll
            for (int k = 0; k < BATCH; k++)
                proc_entry(v[k], ox[k], oy[k], oz[k], qs, tfp, accw, r0, inv_dr, lane);
            #pragma unroll
            for (int k = 0; k < BATCH; k++) v[k] = vn[k];
            base = base_n;
        }
    }
    // tail (partially active waves OK: ballot/shfl use live active mask)
    for (uint e = e0 + nmain + threadIdx.x; e < e1; e += RED_THREADS) {
        uint ev = entries[e];
        uint other = ev >> 7;
        float ox, oy, oz;
        if (USE_Q4) {
            const float* p = (const float*)&q4[other];
            ox = p[0]; oy = p[1]; oz = p[2];
        } else {
            ox = q[3 * other]; oy = q[3 * other + 1]; oz = q[3 * other + 2];
        }
        proc_entry(ev, ox, oy, oz, qs, tfp, accw, r0, inv_dr, lane);
    }

    __syncthreads();
    for (int k = threadIdx.x; k < nA; k += RED_THREADS) {
        float sx = 0.0f, sy = 0.0f, sz = 0.0f;
        #pragma unroll
        for (int rp = 0; rp < NREP; rp++) {
            float4 a = accv[rp * 128 + k];
            sx += a.x; sy += a.y; sz += a.z;
        }
        force[(atomBase + k) * 3 + 0] = sx;
        force[(atomBase + k) * 3 + 1] = sy;
        force[(atomBase + k) * 3 + 2] = sz;
    }
}

// ---------------- fallback: proven global-atomic kernel ----------------
__global__ __launch_bounds__(THREADS) void pair_force_atomic_kernel(
    const float* __restrict__ q, const int2* __restrict__ nbr,
    const float* __restrict__ table_r, const float* __restrict__ table_f,
    float* __restrict__ force, int n_pairs)
{
    __shared__ float tr[N_TABLE];
    __shared__ float tf[N_TABLE];
    for (int k = threadIdx.x; k < N_TABLE; k += THREADS) { tr[k] = table_r[k]; tf[k] = table_f[k]; }
    __syncthreads();
    const float r0 = tr[0], rend = tr[N_TABLE - 1];
    const float inv_dr = (float)(N_TABLE - 1) / (rend - r0);
    int p = blockIdx.x * THREADS + threadIdx.x;
    if (p >= n_pairs) return;
    int2 ij = nbr[p];
    int i = ij.x, j = ij.y;
    float dx = q[3 * i] - q[3 * j], dy = q[3 * i + 1] - q[3 * j + 1], dz = q[3 * i + 2] - q[3 * j + 2];
    dx -= CELL * rintf(dx / CELL); dy -= CELL * rintf(dy / CELL); dz -= CELL * rintf(dz / CELL);
    float r = sqrtf(dx * dx + dy * dy + dz * dz);
    float inv = 1.0f / fmaxf(r, 1e-12f);
    float fm;
    if (r <= r0) fm = tf[0];
    else if (r >= rend) fm = tf[N_TABLE - 1];
    else {
        float t = (r - r0) * inv_dr;
        int idx = min(max((int)t, 0), N_TABLE - 2);
        if (r < tr[idx]) idx = max(idx - 1, 0);
        else if (r >= tr[idx + 1]) idx = min(idx + 1, N_TABLE - 2);
        float rl = tr[idx], rh = tr[idx + 1];
        fm = tf[idx] + (r - rl) * (tf[idx + 1] - tf[idx]) / (rh - rl);
    }
    float s = fm * inv;
    float fx = s * dx, fy = s * dy, fz = s * dz;
    atomicAdd(&force[3 * i + 0], fx); atomicAdd(&force[3 * i + 1], fy); atomicAdd(&force[3 * i + 2], fz);
    atomicAdd(&force[3 * j + 0], -fx); atomicAdd(&force[3 * j + 1], -fy); atomicAdd(&force[3 * j + 2], -fz);
}

extern "C" void kernel_launch(void* const* d_in, const int* in_sizes, int n_in,
                              void* d_out, int out_size, void* d_ws, size_t ws_size,
                              hipStream_t stream) {
    const float* q       = (const float*)d_in[0];
    const int2*  nbr     = (const int2*)d_in[1];
    const float* table_r = (const float*)d_in[2];
    const float* table_f = (const float*)d_in[3];
    float*       force   = (float*)d_out;

    const int n_pairs = in_sizes[1] / 2;
    const int n_atoms = in_sizes[0] / 3;

    // workspace layout (256B-aligned)
    size_t off_partial  = 0;
    size_t off_binTotal = off_partial + (size_t)NB * NBLK * 4;           // 4 MB
    size_t off_binBase  = (off_binTotal + (size_t)NB * 4 + 255) & ~255ull;
    size_t off_entries  = (off_binBase + (size_t)(NB + 1) * 4 + 255) & ~255ull;
    size_t off_q4       = (off_entries + (size_t)2 * n_pairs * 4 + 255) & ~255ull;
    size_t need_base    = off_q4;                       // without q4
    size_t need_q4      = off_q4 + (size_t)n_atoms * 16;

    if (ws_size < need_base || n_atoms > NB * 128) {
        hipMemsetAsync(d_out, 0, (size_t)out_size * sizeof(float), stream);
        int blocks = (n_pairs + THREADS - 1) / THREADS;
        pair_force_atomic_kernel<<<blocks, THREADS, 0, stream>>>(q, nbr, table_r, table_f, force, n_pairs);
        return;
    }

    char* ws = (char*)d_ws;
    uint*   partial  = (uint*)(ws + off_partial);
    uint*   binTotal = (uint*)(ws + off_binTotal);
    uint*   binBase  = (uint*)(ws + off_binBase);
    uint*   entries  = (uint*)(ws + off_entries);
    float4* q4       = (float4*)(ws + off_q4);
    int use_q4 = (ws_size >= need_q4) ? 1 : 0;

    int ppb = (((n_pairs + NBLK - 1) / NBLK) + 1) & ~1;   // even pairs per block

    if (use_q4) {
        int pb = (n_atoms + THREADS - 1) / THREADS;
        pack_q4_kernel<<<pb, THREADS, 0, stream>>>(q, q4, n_atoms);
    }
    hist_kernel<<<NBLK, THREADS, 0, stream>>>(nbr, partial, n_pairs, ppb);
    scan_rows_kernel<<<NB, THREADS, 0, stream>>>(partial, binTotal);
    scan_totals_kernel<<<1, THREADS, 0, stream>>>(binTotal, binBase);
    scatter_kernel<<<NBLK, THREADS, 0, stream>>>(nbr, partial, binBase, entries, n_pairs, ppb);
    if (use_q4)
        reduce_kernel<1><<<NB, RED_THREADS, 0, stream>>>(q, q4, table_r, table_f, binBase, entries, force, n_atoms);
    else
        reduce_kernel<0><<<NB, RED_THREADS, 0, stream>>>(q, q4, table_r, table_f, binBase, entries, force, n_atoms);
}

// Round 10
// 222.942 us; speedup vs baseline: 2.2698x; 1.0518x over previous
//
#include <hip/hip_runtime.h>

#define CELL 50.0f
#define N_TABLE 1024
#define NB 1024            // buckets of 128 atoms each (max 131072 atoms)
#define NBLK 512           // histogram/scatter blocks
#define THREADS 256
#define SCAT_THREADS 512
#define LBUF_CAP 25088     // max entries per scatter block (2*ppb)
#define RED_THREADS 512
#define NREP 8             // one acc replica per wave in reduce (REQUIRED: wave-private)
#define BATCH 6            // entries per thread per chunk in reduce

typedef unsigned int uint;

// ---------------- K0: pack q into float4 ----------------
__global__ __launch_bounds__(THREADS) void pack_q4_kernel(
    const float* __restrict__ q, float4* __restrict__ q4, int n_atoms)
{
    int i = blockIdx.x * THREADS + threadIdx.x;
    if (i < n_atoms)
        q4[i] = make_float4(q[3 * i], q[3 * i + 1], q[3 * i + 2], 0.0f);
}

// ---------------- K1: per-block bucket histogram (int4 loads) ----------------
// Writes BOTH the scan-layout partial[k*NBLK+blk] and raw rawh[blk*NB+k].
__global__ __launch_bounds__(THREADS) void hist_kernel(
    const int2* __restrict__ nbr, uint* __restrict__ partial,
    uint* __restrict__ rawh, int n_pairs, int ppb)
{
    __shared__ uint h[NB];
    for (int k = threadIdx.x; k < NB; k += THREADS) h[k] = 0;
    __syncthreads();
    int start = blockIdx.x * ppb;                 // ppb even -> start even
    int end   = min(start + ppb, n_pairs & ~1);
    const int4* nbr4 = (const int4*)nbr;
    for (int p2 = (start >> 1) + threadIdx.x; p2 < (end >> 1); p2 += THREADS) {
        int4 v = nbr4[p2];
        atomicAdd(&h[((uint)v.x) >> 7], 1u);
        atomicAdd(&h[((uint)v.y) >> 7], 1u);
        atomicAdd(&h[((uint)v.z) >> 7], 1u);
        atomicAdd(&h[((uint)v.w) >> 7], 1u);
    }
    if (blockIdx.x == 0 && threadIdx.x == 0 && (n_pairs & 1)) {
        int2 ij = nbr[n_pairs - 1];
        atomicAdd(&h[((uint)ij.x) >> 7], 1u);
        atomicAdd(&h[((uint)ij.y) >> 7], 1u);
    }
    __syncthreads();
    for (int k = threadIdx.x; k < NB; k += THREADS) {
        uint c = h[k];
        partial[k * NBLK + blockIdx.x] = c;
        rawh[blockIdx.x * NB + k]      = c;
    }
}

// ---------------- K2a: per-bucket exclusive scan over block partials ----------------
__global__ __launch_bounds__(THREADS) void scan_rows_kernel(
    uint* __restrict__ partial, uint* __restrict__ binTotal)
{
    __shared__ uint s[THREADS];
    int bin = blockIdx.x;
    uint running = 0;
    for (int c = 0; c < NBLK / THREADS; c++) {
        int idx = bin * NBLK + c * THREADS + threadIdx.x;
        uint v = partial[idx];
        s[threadIdx.x] = v;
        __syncthreads();
        for (int off = 1; off < THREADS; off <<= 1) {
            uint t = (threadIdx.x >= (uint)off) ? s[threadIdx.x - off] : 0u;
            __syncthreads();
            s[threadIdx.x] += t;
            __syncthreads();
        }
        partial[idx] = running + s[threadIdx.x] - v;   // exclusive within bin
        uint csum = s[THREADS - 1];
        __syncthreads();
        running += csum;
    }
    if (threadIdx.x == 0) binTotal[bin] = running;
}

// ---------------- K2b: exclusive scan of bucket totals ----------------
__global__ __launch_bounds__(THREADS) void scan_totals_kernel(
    const uint* __restrict__ binTotal, uint* __restrict__ binBase)
{
    __shared__ uint s[THREADS];
    uint v[4];
    uint sum = 0;
    int base = threadIdx.x * 4;
    for (int k = 0; k < 4; k++) { v[k] = binTotal[base + k]; sum += v[k]; }
    s[threadIdx.x] = sum;
    __syncthreads();
    for (int off = 1; off < THREADS; off <<= 1) {
        uint t = (threadIdx.x >= (uint)off) ? s[threadIdx.x - off] : 0u;
        __syncthreads();
        s[threadIdx.x] += t;
        __syncthreads();
    }
    uint run = s[threadIdx.x] - sum;
    for (int k = 0; k < 4; k++) { binBase[base + k] = run; run += v[k]; }
    if (threadIdx.x == THREADS - 1) binBase[NB] = run;
}

// ---------------- K3: LDS-sorted scatter (coalesced run writes) ----------------
// Bin this block's entries into LDS by bucket, then stream each bucket's run out
// contiguously. Final global layout identical to the unsorted scatter.
__global__ __launch_bounds__(SCAT_THREADS) void scatter_sorted_kernel(
    const int2* __restrict__ nbr, const uint* __restrict__ rawh,
    const uint* __restrict__ partial, const uint* __restrict__ binBase,
    uint* __restrict__ entries, int n_pairs, int ppb)
{
    __shared__ uint lbuf[LBUF_CAP];
    __shared__ uint localBase[NB];
    __shared__ uint lcur[NB];
    __shared__ uint ssc[SCAT_THREADS];

    int tid = threadIdx.x;
    int blk = blockIdx.x;

    // per-block histogram -> exclusive scan (2 buckets per thread)
    uint v0 = rawh[blk * NB + 2 * tid];
    uint v1 = rawh[blk * NB + 2 * tid + 1];
    uint sum2 = v0 + v1;
    ssc[tid] = sum2;
    __syncthreads();
    for (int off = 1; off < SCAT_THREADS; off <<= 1) {
        uint t = (tid >= off) ? ssc[tid - off] : 0u;
        __syncthreads();
        ssc[tid] += t;
        __syncthreads();
    }
    uint base = ssc[tid] - sum2;
    localBase[2 * tid]     = base;      lcur[2 * tid]     = base;
    localBase[2 * tid + 1] = base + v0; lcur[2 * tid + 1] = base + v0;
    __syncthreads();

    // bin entries into LDS
    int start = blk * ppb;
    int end   = min(start + ppb, n_pairs & ~1);
    const int4* nbr4 = (const int4*)nbr;
    for (int p2 = (start >> 1) + tid; p2 < (end >> 1); p2 += SCAT_THREADS) {
        int4 v = nbr4[p2];
        uint i0 = (uint)v.x, j0 = (uint)v.y, i1 = (uint)v.z, j1 = (uint)v.w;
        uint o;
        o = atomicAdd(&lcur[i0 >> 7], 1u); lbuf[o] = (j0 << 7) | (i0 & 127u);
        o = atomicAdd(&lcur[j0 >> 7], 1u); lbuf[o] = (i0 << 7) | (j0 & 127u);
        o = atomicAdd(&lcur[i1 >> 7], 1u); lbuf[o] = (j1 << 7) | (i1 & 127u);
        o = atomicAdd(&lcur[j1 >> 7], 1u); lbuf[o] = (i1 << 7) | (j1 & 127u);
    }
    if (blk == 0 && tid == 0 && (n_pairs & 1)) {
        int2 ij = nbr[n_pairs - 1];
        uint i = (uint)ij.x, j = (uint)ij.y;
        uint o;
        o = atomicAdd(&lcur[i >> 7], 1u); lbuf[o] = (j << 7) | (i & 127u);
        o = atomicAdd(&lcur[j >> 7], 1u); lbuf[o] = (i << 7) | (j & 127u);
    }
    __syncthreads();

    // wave-per-bucket coalesced copy-out
    int wave = tid >> 6, lane = tid & 63;
    for (int b = wave; b < NB; b += SCAT_THREADS / 64) {
        uint lb  = localBase[b];
        uint cnt = lcur[b] - lb;
        if (!cnt) continue;
        uint gdst = binBase[b] + partial[b * NBLK + blk];
        for (uint o = lane; o < cnt; o += 64)
            entries[gdst + o] = lbuf[lb + o];
    }
}

// ---------------- K3-fallback: unsorted scatter (if LBUF too small) ----------------
__global__ __launch_bounds__(THREADS) void scatter_plain_kernel(
    const int2* __restrict__ nbr, const uint* __restrict__ partial,
    const uint* __restrict__ binBase, uint* __restrict__ entries,
    int n_pairs, int ppb)
{
    __shared__ uint cur[NB];
    for (int k = threadIdx.x; k < NB; k += THREADS)
        cur[k] = binBase[k] + partial[k * NBLK + blockIdx.x];
    __syncthreads();
    int start = blockIdx.x * ppb;
    int end   = min(start + ppb, n_pairs & ~1);
    const int4* nbr4 = (const int4*)nbr;
    for (int p2 = (start >> 1) + threadIdx.x; p2 < (end >> 1); p2 += THREADS) {
        int4 v = nbr4[p2];
        uint i0 = (uint)v.x, j0 = (uint)v.y, i1 = (uint)v.z, j1 = (uint)v.w;
        uint p;
        p = atomicAdd(&cur[i0 >> 7], 1u); entries[p] = (j0 << 7) | (i0 & 127u);
        p = atomicAdd(&cur[j0 >> 7], 1u); entries[p] = (i0 << 7) | (j0 & 127u);
        p = atomicAdd(&cur[i1 >> 7], 1u); entries[p] = (j1 << 7) | (i1 & 127u);
        p = atomicAdd(&cur[j1 >> 7], 1u); entries[p] = (i1 << 7) | (j1 & 127u);
    }
    if (blockIdx.x == 0 && threadIdx.x == 0 && (n_pairs & 1)) {
        int2 ij = nbr[n_pairs - 1];
        uint i = (uint)ij.x, j = (uint)ij.y;
        uint p;
        p = atomicAdd(&cur[i >> 7], 1u); entries[p] = (j << 7) | (i & 127u);
        p = atomicAdd(&cur[j >> 7], 1u); entries[p] = (i << 7) | (j & 127u);
    }
}

// ---------------- K4: per-bucket reduce (ballot-group + leader-shfl, ZERO atomics) ----------------
__device__ __forceinline__ void proc_entry(
    uint ev, float ox, float oy, float oz,
    const float4* __restrict__ qs, const float2* __restrict__ tfp,
    float4* __restrict__ accw, float r0, float inv_dr, int lane)
{
    int local = (int)(ev & 127u);
    float4 m = qs[local];
    float dx = m.x - ox, dy = m.y - oy, dz = m.z - oz;
    // exact minimum image for d in (-50,50): round-half-even boundary at +/-25.0
    dx -= (dx > 25.0f) ? 50.0f : ((dx < -25.0f) ? -50.0f : 0.0f);
    dy -= (dy > 25.0f) ? 50.0f : ((dy < -25.0f) ? -50.0f : 0.0f);
    dz -= (dz > 25.0f) ? 50.0f : ((dz < -25.0f) ? -50.0f : 0.0f);
    float r2 = dx * dx + dy * dy + dz * dz;
    float rs = __builtin_amdgcn_rsqf(fmaxf(r2, 1e-24f));   // ~1ulp v_rsq_f32
    float r  = r2 * rs;                                    // r = sqrt(r2)
    float t  = (r - r0) * inv_dr;
    t = fminf(fmaxf(t, 0.0f), 1023.0f);
    int idx = min((int)t, N_TABLE - 2);
    float frac = t - (float)idx;
    float2 tp = tfp[idx];
    float s = (tp.x + frac * tp.y) * rs;                   // fm / r
    float fx = s * dx, fy = s * dy, fz = s * dz;

    // 7-bit ballot grouping of `local` within the wave
    unsigned long long m64 = __ballot(1);
    #pragma unroll
    for (int b = 0; b < 7; b++) {
        unsigned long long bb = __ballot((local >> b) & 1);
        m64 &= ((local >> b) & 1) ? bb : ~bb;
    }
    unsigned long long self = 1ull << lane;
    bool leader = ((m64 & (self - 1ull)) == 0ull);
    unsigned long long rem = leader ? (m64 & ~self) : 0ull;

    while (__any(rem != 0ull)) {
        int src = rem ? (int)__builtin_ctzll(rem) : lane;
        float px = __shfl(fx, src);
        float py = __shfl(fy, src);
        float pz = __shfl(fz, src);
        if (rem) {
            fx += px; fy += py; fz += pz;
            rem &= rem - 1ull;
        }
    }
    if (leader) {
        float4 a = accw[local];
        a.x += fx; a.y += fy; a.z += fz;
        accw[local] = a;
    }
}

template<int USE_Q4>
__global__ __launch_bounds__(RED_THREADS, 8) void reduce_kernel(
    const float* __restrict__ q, const float4* __restrict__ q4,
    const float* __restrict__ table_r, const float* __restrict__ table_f,
    const uint* __restrict__ binBase, const uint* __restrict__ entries,
    float* __restrict__ force, int n_atoms)
{
    __shared__ float2 tfp[N_TABLE];        // (f[i], f[i+1]-f[i])   8 KB
    __shared__ float4 qs[128];             //                       2 KB
    __shared__ float4 accv[NREP * 128];    // wave-private replicas 16 KB

    int b = blockIdx.x;
    int atomBase = b << 7;
    if (atomBase >= n_atoms) return;
    int nA = min(128, n_atoms - atomBase);
    int lane = threadIdx.x & 63;

    const float r0     = table_r[0];
    const float rend   = table_r[N_TABLE - 1];
    const float inv_dr = (float)(N_TABLE - 1) / (rend - r0);

    for (int k = threadIdx.x; k < N_TABLE - 1; k += RED_THREADS) {
        float a = table_f[k], c = table_f[k + 1];
        tfp[k] = make_float2(a, c - a);
    }
    for (int k = threadIdx.x; k < nA; k += RED_THREADS) {
        if (USE_Q4) qs[k] = q4[atomBase + k];
        else qs[k] = make_float4(q[(atomBase + k) * 3], q[(atomBase + k) * 3 + 1],
                                 q[(atomBase + k) * 3 + 2], 0.0f);
    }
    for (int k = threadIdx.x; k < NREP * 128; k += RED_THREADS)
        accv[k] = make_float4(0.0f, 0.0f, 0.0f, 0.0f);
    __syncthreads();

    float4* accw = &accv[(threadIdx.x >> 6) * 128];

    uint e0 = binBase[b], e1 = binBase[b + 1];
    uint count = e1 - e0;
    const uint CHUNK = BATCH * RED_THREADS;
    uint nmain = (count / CHUNK) * CHUNK;

    if (nmain) {
        uint v[BATCH];
        #pragma unroll
        for (int k = 0; k < BATCH; k++)
            v[k] = entries[e0 + threadIdx.x + k * RED_THREADS];

        for (uint base = 0; base < nmain; ) {
            float ox[BATCH], oy[BATCH], oz[BATCH];
            #pragma unroll
            for (int k = 0; k < BATCH; k++) {
                uint other = v[k] >> 7;
                if (USE_Q4) {
                    const float* p = (const float*)&q4[other];
                    ox[k] = p[0]; oy[k] = p[1]; oz[k] = p[2];
                } else {
                    ox[k] = q[3 * other]; oy[k] = q[3 * other + 1]; oz[k] = q[3 * other + 2];
                }
            }
            uint base_n = base + CHUNK;
            uint vn[BATCH];
            if (base_n < nmain) {
                #pragma unroll
                for (int k = 0; k < BATCH; k++)
                    vn[k] = entries[e0 + base_n + threadIdx.x + k * RED_THREADS];
            } else {
                #pragma unroll
                for (int k = 0; k < BATCH; k++) vn[k] = 0u;
            }
            #pragma unroll
            for (int k = 0; k < BATCH; k++)
                proc_entry(v[k], ox[k], oy[k], oz[k], qs, tfp, accw, r0, inv_dr, lane);
            #pragma unroll
            for (int k = 0; k < BATCH; k++) v[k] = vn[k];
            base = base_n;
        }
    }
    // tail
    for (uint e = e0 + nmain + threadIdx.x; e < e1; e += RED_THREADS) {
        uint ev = entries[e];
        uint other = ev >> 7;
        float ox, oy, oz;
        if (USE_Q4) {
            const float* p = (const float*)&q4[other];
            ox = p[0]; oy = p[1]; oz = p[2];
        } else {
            ox = q[3 * other]; oy = q[3 * other + 1]; oz = q[3 * other + 2];
        }
        proc_entry(ev, ox, oy, oz, qs, tfp, accw, r0, inv_dr, lane);
    }

    __syncthreads();
    for (int k = threadIdx.x; k < nA; k += RED_THREADS) {
        float sx = 0.0f, sy = 0.0f, sz = 0.0f;
        #pragma unroll
        for (int rp = 0; rp < NREP; rp++) {
            float4 a = accv[rp * 128 + k];
            sx += a.x; sy += a.y; sz += a.z;
        }
        force[(atomBase + k) * 3 + 0] = sx;
        force[(atomBase + k) * 3 + 1] = sy;
        force[(atomBase + k) * 3 + 2] = sz;
    }
}

// ---------------- fallback: proven global-atomic kernel ----------------
__global__ __launch_bounds__(THREADS) void pair_force_atomic_kernel(
    const float* __restrict__ q, const int2* __restrict__ nbr,
    const float* __restrict__ table_r, const float* __restrict__ table_f,
    float* __restrict__ force, int n_pairs)
{
    __shared__ float tr[N_TABLE];
    __shared__ float tf[N_TABLE];
    for (int k = threadIdx.x; k < N_TABLE; k += THREADS) { tr[k] = table_r[k]; tf[k] = table_f[k]; }
    __syncthreads();
    const float r0 = tr[0], rend = tr[N_TABLE - 1];
    const float inv_dr = (float)(N_TABLE - 1) / (rend - r0);
    int p = blockIdx.x * THREADS + threadIdx.x;
    if (p >= n_pairs) return;
    int2 ij = nbr[p];
    int i = ij.x, j = ij.y;
    float dx = q[3 * i] - q[3 * j], dy = q[3 * i + 1] - q[3 * j + 1], dz = q[3 * i + 2] - q[3 * j + 2];
    dx -= CELL * rintf(dx / CELL); dy -= CELL * rintf(dy / CELL); dz -= CELL * rintf(dz / CELL);
    float r = sqrtf(dx * dx + dy * dy + dz * dz);
    float inv = 1.0f / fmaxf(r, 1e-12f);
    float fm;
    if (r <= r0) fm = tf[0];
    else if (r >= rend) fm = tf[N_TABLE - 1];
    else {
        float t = (r - r0) * inv_dr;
        int idx = min(max((int)t, 0), N_TABLE - 2);
        if (r < tr[idx]) idx = max(idx - 1, 0);
        else if (r >= tr[idx + 1]) idx = min(idx + 1, N_TABLE - 2);
        float rl = tr[idx], rh = tr[idx + 1];
        fm = tf[idx] + (r - rl) * (tf[idx + 1] - tf[idx]) / (rh - rl);
    }
    float s = fm * inv;
    float fx = s * dx, fy = s * dy, fz = s * dz;
    atomicAdd(&force[3 * i + 0], fx); atomicAdd(&force[3 * i + 1], fy); atomicAdd(&force[3 * i + 2], fz);
    atomicAdd(&force[3 * j + 0], -fx); atomicAdd(&force[3 * j + 1], -fy); atomicAdd(&force[3 * j + 2], -fz);
}

extern "C" void kernel_launch(void* const* d_in, const int* in_sizes, int n_in,
                              void* d_out, int out_size, void* d_ws, size_t ws_size,
                              hipStream_t stream) {
    const float* q       = (const float*)d_in[0];
    const int2*  nbr     = (const int2*)d_in[1];
    const float* table_r = (const float*)d_in[2];
    const float* table_f = (const float*)d_in[3];
    float*       force   = (float*)d_out;

    const int n_pairs = in_sizes[1] / 2;
    const int n_atoms = in_sizes[0] / 3;

    // workspace layout (256B-aligned)
    size_t off_partial  = 0;
    size_t off_rawh     = (off_partial + (size_t)NB * NBLK * 4 + 255) & ~255ull;   // 2 MB
    size_t off_binTotal = (off_rawh + (size_t)NB * NBLK * 4 + 255) & ~255ull;      // +2 MB
    size_t off_binBase  = (off_binTotal + (size_t)NB * 4 + 255) & ~255ull;
    size_t off_entries  = (off_binBase + (size_t)(NB + 1) * 4 + 255) & ~255ull;
    size_t off_q4       = (off_entries + (size_t)2 * n_pairs * 4 + 255) & ~255ull;
    size_t need_base    = off_q4;                       // without q4
    size_t need_q4      = off_q4 + (size_t)n_atoms * 16;

    if (ws_size < need_base || n_atoms > NB * 128) {
        hipMemsetAsync(d_out, 0, (size_t)out_size * sizeof(float), stream);
        int blocks = (n_pairs + THREADS - 1) / THREADS;
        pair_force_atomic_kernel<<<blocks, THREADS, 0, stream>>>(q, nbr, table_r, table_f, force, n_pairs);
        return;
    }

    char* ws = (char*)d_ws;
    uint*   partial  = (uint*)(ws + off_partial);
    uint*   rawh     = (uint*)(ws + off_rawh);
    uint*   binTotal = (uint*)(ws + off_binTotal);
    uint*   binBase  = (uint*)(ws + off_binBase);
    uint*   entries  = (uint*)(ws + off_entries);
    float4* q4       = (float4*)(ws + off_q4);
    int use_q4 = (ws_size >= need_q4) ? 1 : 0;

    int ppb = (((n_pairs + NBLK - 1) / NBLK) + 1) & ~1;   // even pairs per block

    if (use_q4) {
        int pb = (n_atoms + THREADS - 1) / THREADS;
        pack_q4_kernel<<<pb, THREADS, 0, stream>>>(q, q4, n_atoms);
    }
    hist_kernel<<<NBLK, THREADS, 0, stream>>>(nbr, partial, rawh, n_pairs, ppb);
    scan_rows_kernel<<<NB, THREADS, 0, stream>>>(partial, binTotal);
    scan_totals_kernel<<<1, THREADS, 0, stream>>>(binTotal, binBase);
    if (2 * ppb <= LBUF_CAP)
        scatter_sorted_kernel<<<NBLK, SCAT_THREADS, 0, stream>>>(
            nbr, rawh, partial, binBase, entries, n_pairs, ppb);
    else
        scatter_plain_kernel<<<NBLK, THREADS, 0, stream>>>(
            nbr, partial, binBase, entries, n_pairs, ppb);
    if (use_q4)
        reduce_kernel<1><<<NB, RED_THREADS, 0, stream>>>(q, q4, table_r, table_f, binBase, entries, force, n_atoms);
    else
        reduce_kernel<0><<<NB, RED_THREADS, 0, stream>>>(q, q4, table_r, table_f, binBase, entries, force, n_atoms);
}